// Round 10
// baseline (179.975 us; speedup 1.0000x reference)
//
#include <hip/hip_runtime.h>

#define BB   8192   // batch (M)
#define DIN  4096   // K
#define DOUT 2048   // N

typedef unsigned short ushort_t;
typedef __attribute__((ext_vector_type(8))) short bf16x8;   // 8 bf16 (4 VGPRs)
typedef __attribute__((ext_vector_type(4))) float f32x4;    // 4 fp32 acc

// round-to-nearest-even fp32 -> bf16 bits
__device__ inline ushort_t f2bf(float f) {
    union { float f; unsigned u; } v; v.f = f;
    unsigned u = v.u;
    return (ushort_t)((u + 0x7fffu + ((u >> 16) & 1u)) >> 16);
}

// async global->LDS, 16B per lane; LDS dest = wave-uniform base (+lane*16 implicit)
#define GLOAD16(g, s)                                                        \
    __builtin_amdgcn_global_load_lds(                                        \
        (const __attribute__((address_space(1))) void*)(g),                  \
        (__attribute__((address_space(3))) void*)(s), 16, 0, 0)

#define FENCE() asm volatile("" ::: "memory")
#define BAR()   do { FENCE(); __builtin_amdgcn_s_barrier(); FENCE(); } while (0)
#define VMCNT(n) asm volatile("s_waitcnt vmcnt(" #n ")" ::: "memory")

// ---------------- pre-pass 1: inputs fp32 -> bf16 ----------------
struct __align__(8) us4 { ushort_t x, y, z, w; };

__global__ __launch_bounds__(256) void convA(const float4* __restrict__ in,
                                             us4* __restrict__ out, int n4) {
    int i = blockIdx.x * blockDim.x + threadIdx.x;
    int stride = gridDim.x * blockDim.x;
    for (; i < n4; i += stride) {
        float4 v = in[i];
        us4 o;
        o.x = f2bf(v.x); o.y = f2bf(v.y); o.z = f2bf(v.z); o.w = f2bf(v.w);
        out[i] = o;
    }
}

// ---------------- pre-pass 2: WT[n][k] = bf16(kernel[k][n]*map[k][n]) ----------------
__global__ __launch_bounds__(256) void maskT(const float* __restrict__ Kn,
                                             const float* __restrict__ Mp,
                                             ushort_t* __restrict__ WT) {
    __shared__ ushort_t t[32][33];
    const int n0 = blockIdx.x * 32;
    const int k0 = blockIdx.y * 32;
    const int tx = threadIdx.x, ty = threadIdx.y;
    #pragma unroll
    for (int i = ty; i < 32; i += 8) {
        size_t idx = (size_t)(k0 + i) * DOUT + (n0 + tx);
        t[i][tx] = f2bf(Kn[idx] * Mp[idx]);
    }
    __syncthreads();
    #pragma unroll
    for (int i = ty; i < 32; i += 8) {
        WT[(size_t)(n0 + i) * DIN + (k0 + tx)] = t[tx][i];
    }
}

// ---------------- main GEMM: 256x128 tile, BK=32, 4 waves, 2 blocks/CU ----------------
// Occupancy lever: 256 threads + 72KiB LDS -> 2 independent blocks/CU; their
// waves are NOT barrier-synced with each other, so one block's MFMA fills the
// other's waitcnt/barrier stalls (m114 co-scheduling).
// 3 buffers x 24KiB; tile t stages t+2 (6 gload_lds/wave, issue-early); ONE
// VMCNT(6)+BAR per tile (never drains; retire exactly t+1's 6 loads).
// LDS packing (128B rows at BK=32): pair p holds [row p | row p+PAIRS] x 32k;
// stored slot = logical ^ (p&7), logical = hf*4 + col16. Inverse on global
// source (DMA dest linear, rule 21); frag reads XOR (l15&7) -> <=2-way (free).
// Buffer b: A (128 pairs, 16KB) at b*24576; B (64 pairs, 8KB) at +16384.
__global__ __launch_bounds__(256, 2) void gemm8(const ushort_t* __restrict__ A,   // [M][K]
                                                const ushort_t* __restrict__ BT,  // [N][K]
                                                const float* __restrict__ bias,   // [N]
                                                float* __restrict__ C) {          // [M][N]
    constexpr int K = DIN, N = DOUT;
    constexpr int NT = K / 32;           // 128 K-tiles of BK=32
    extern __shared__ char sb[];         // 72 KiB

    const int tid  = threadIdx.x;
    const int lane = tid & 63;
    const int w    = tid >> 6;           // wave 0..3
    const int wr   = w >> 1;             // 0..1  (M half: rows wr*128..+127)
    const int wc   = w & 1;              // 0..1  (N half: cols wc*64..+63)
    const int l15  = lane & 15;

    // bijective XCD swizzle: 512 blocks, 512 % 8 == 0
    const int orig = blockIdx.y * 16 + blockIdx.x;
    const int wg   = (orig & 7) * 64 + (orig >> 3);
    const int n0   = (wg & 15) * 128;    // N tile (16 of)
    const int m0   = (wg >> 4) * 256;    // M tile (32 of)

    // ---- staging source: chunk c = pairs c*8..c*8+7; lane l -> pair c*8+(l>>3),
    // stored slot l&7; logical sl = (l&7)^(l>>3): hf = sl>>2, col16 = sl&3.
    const int sl   = (lane & 7) ^ (lane >> 3);
    const int sroA = (sl >> 2) * 128 + (lane >> 3);   // A: PAIRS=128
    const int sroB = (sl >> 2) * 64 + (lane >> 3);    // B: PAIRS=64
    const int sco  = (sl & 3) * 8;                    // bf16 elements
    const ushort_t* Ab = A  + (size_t)(m0 + sroA) * K + sco;
    const ushort_t* Bb = BT + (size_t)(n0 + sroB) * K + sco;

    auto stgA = [&](int buf, int kt, int c) {   // c in 0..15
        GLOAD16(Ab + (size_t)(c * 8) * K + kt * 32, sb + buf * 24576 + c * 1024);
    };
    auto stgB = [&](int buf, int kt, int c) {   // c in 0..7
        GLOAD16(Bb + (size_t)(c * 8) * K + kt * 32, sb + buf * 24576 + 16384 + c * 1024);
    };

    // ---- fragment ds_read offsets ----
    // A frag fm: pair = fm*16+l15, hf=wr -> slot = (wr*4 + (lane>>4)) ^ (l15&7)
    const int aoff = l15 * 128 + ((((wr << 2) | (lane >> 4)) ^ (l15 & 7)) << 4);
    // B frag fn: pair = fn*16+l15, hf=wc
    const int boff = 16384 + l15 * 128 + ((((wc << 2) | (lane >> 4)) ^ (l15 & 7)) << 4);

    f32x4 acc[8][4] = {};   // 8 m-frags x 4 n-frags

#define TILE(T, CURB, STGB, DOPF, WAITK)                                       \
    {                                                                          \
        if (DOPF) {                                                            \
            stgA(STGB, (T) + 2, w);      stgA(STGB, (T) + 2, 4 + w);           \
            stgA(STGB, (T) + 2, 8 + w);  stgA(STGB, (T) + 2, 12 + w);          \
            stgB(STGB, (T) + 2, w);      stgB(STGB, (T) + 2, 4 + w);           \
        }                                                                      \
        const char* base_ = sb + (CURB) * 24576;                               \
        bf16x8 bfk[4], af[8];                                                  \
        _Pragma("unroll")                                                      \
        for (int fn = 0; fn < 4; ++fn)                                         \
            bfk[fn] = *(const bf16x8*)(base_ + fn * 2048 + boff);              \
        _Pragma("unroll")                                                      \
        for (int fm = 0; fm < 8; ++fm)                                         \
            af[fm] = *(const bf16x8*)(base_ + fm * 2048 + aoff);               \
        __builtin_amdgcn_s_setprio(1);                                         \
        _Pragma("unroll")                                                      \
        for (int fm = 0; fm < 8; ++fm)                                         \
            _Pragma("unroll")                                                  \
            for (int fn = 0; fn < 4; ++fn)                                     \
                acc[fm][fn] = __builtin_amdgcn_mfma_f32_16x16x32_bf16(         \
                    af[fm], bfk[fn], acc[fm][fn], 0, 0, 0);                    \
        __builtin_amdgcn_s_setprio(0);                                         \
        if ((WAITK) == 6) { VMCNT(6); }                                        \
        else if ((WAITK) == 0) { VMCNT(0); }                                   \
        BAR();                                                                 \
    }

    // ---- prologue: stage tiles 0 -> buf0, 1 -> buf1 ----
    stgA(0, 0, w); stgA(0, 0, 4 + w); stgA(0, 0, 8 + w); stgA(0, 0, 12 + w);
    stgB(0, 0, w); stgB(0, 0, 4 + w);
    stgA(1, 1, w); stgA(1, 1, 4 + w); stgA(1, 1, 8 + w); stgA(1, 1, 12 + w);
    stgB(1, 1, w); stgB(1, 1, 4 + w);
    VMCNT(6);   // tile 0's 6 retired; tile 1's 6 in flight
    BAR();

    // ---- main loop: unroll x3 for compile-time buffer rotation ----
    for (int tb = 0; tb < NT - 2; tb += 3) {
        TILE(tb + 0, 0, 2, 1, 6);
        TILE(tb + 1, 1, 0, 1, 6);
        TILE(tb + 2, 2, 1, 1, 6);
    }
    TILE(NT - 2, 0, 2, 0, 0);    // 126: reads buf0, drain t=127's loads
    TILE(NT - 1, 1, 0, 0, -1);   // 127: reads buf1, no wait
#undef TILE

    // ---- epilogue: C/D layout col=lane&15, row=(lane>>4)*4+j; fused bias ----
    #pragma unroll
    for (int n = 0; n < 4; ++n) {
        const int col = n0 + wc * 64 + n * 16 + l15;
        const float bv = bias[col];
        #pragma unroll
        for (int m = 0; m < 8; ++m) {
            const int r0 = m0 + wr * 128 + m * 16 + (lane >> 4) * 4;
            #pragma unroll
            for (int j = 0; j < 4; ++j)
                C[(size_t)(r0 + j) * N + col] = acc[m][n][j] + bv;
        }
    }
}

// ---------------- fallback (ws too small): fp32 LDS-tiled GEMM ----------------
__global__ __launch_bounds__(1024) void gemm_fb(const float* __restrict__ A,
                                                const float* __restrict__ Kn,
                                                const float* __restrict__ Mp,
                                                const float* __restrict__ bias,
                                                float* __restrict__ C) {
    __shared__ float As[32][33];
    __shared__ float Bs[32][33];
    const int tx = threadIdx.x, ty = threadIdx.y;
    const int row = blockIdx.y * 32 + ty;
    const int col = blockIdx.x * 32 + tx;
    float acc = 0.f;
    for (int kt = 0; kt < DIN; kt += 32) {
        As[ty][tx] = A[(size_t)row * DIN + kt + tx];
        size_t bidx = (size_t)(kt + ty) * DOUT + col;
        Bs[ty][tx] = Kn[bidx] * Mp[bidx];
        __syncthreads();
        #pragma unroll
        for (int kk = 0; kk < 32; ++kk)
            acc += As[ty][kk] * Bs[kk][tx];
        __syncthreads();
    }
    C[(size_t)row * DOUT + col] = acc + bias[col];
}

extern "C" void kernel_launch(void* const* d_in, const int* in_sizes, int n_in,
                              void* d_out, int out_size, void* d_ws, size_t ws_size,
                              hipStream_t stream) {
    const float* inputs = (const float*)d_in[0];   // [8192,4096]
    const float* kernel = (const float*)d_in[1];   // [4096,2048]
    const float* bias   = (const float*)d_in[2];   // [2048]
    const float* map    = (const float*)d_in[3];   // [4096,2048]
    float* out = (float*)d_out;                    // [8192,2048]

    const size_t abytes = (size_t)BB * DIN * sizeof(ushort_t);   // 64 MiB
    const size_t wbytes = (size_t)DIN * DOUT * sizeof(ushort_t); // 16 MiB

    if (ws_size >= abytes + wbytes) {
        ushort_t* Abf = (ushort_t*)d_ws;
        ushort_t* WT  = (ushort_t*)((char*)d_ws + abytes);

        static bool attr_set = false;
        if (!attr_set) {
            hipFuncSetAttribute((const void*)gemm8,
                                hipFuncAttributeMaxDynamicSharedMemorySize, 73728);
            attr_set = true;
        }

        convA<<<2048, 256, 0, stream>>>((const float4*)inputs, (us4*)Abf,
                                        (int)((size_t)BB * DIN / 4));
        maskT<<<dim3(DOUT / 32, DIN / 32), dim3(32, 8), 0, stream>>>(kernel, map, WT);
        gemm8<<<dim3(DOUT / 128, BB / 256), 256, 73728, stream>>>(Abf, WT, bias, out);
    } else {
        gemm_fb<<<dim3(DOUT / 32, BB / 32), dim3(32, 32), 0, stream>>>(inputs, kernel, map,
                                                                       bias, out);
    }
}

// Round 11
// 165.599 us; speedup vs baseline: 1.0868x; 1.0868x over previous
//
#include <hip/hip_runtime.h>

#define BB   8192   // batch (M)
#define DIN  4096   // K
#define DOUT 2048   // N

typedef unsigned short ushort_t;
typedef __attribute__((ext_vector_type(8))) short bf16x8;   // 8 bf16 (4 VGPRs)
typedef __attribute__((ext_vector_type(4))) float f32x4;    // 4 fp32 acc

// round-to-nearest-even fp32 -> bf16 bits
__device__ inline ushort_t f2bf(float f) {
    union { float f; unsigned u; } v; v.f = f;
    unsigned u = v.u;
    return (ushort_t)((u + 0x7fffu + ((u >> 16) & 1u)) >> 16);
}

// async global->LDS, 16B per lane; LDS dest = wave-uniform base (+lane*16 implicit)
#define GLOAD16(g, s)                                                        \
    __builtin_amdgcn_global_load_lds(                                        \
        (const __attribute__((address_space(1))) void*)(g),                  \
        (__attribute__((address_space(3))) void*)(s), 16, 0, 0)

#define FENCE() asm volatile("" ::: "memory")
#define BAR()   do { FENCE(); __builtin_amdgcn_s_barrier(); FENCE(); } while (0)
#define VMCNT(n) asm volatile("s_waitcnt vmcnt(" #n ")" ::: "memory")

// ---------------- pre-pass 1: inputs fp32 -> bf16 ----------------
struct __align__(8) us4 { ushort_t x, y, z, w; };

__global__ __launch_bounds__(256) void convA(const float4* __restrict__ in,
                                             us4* __restrict__ out, int n4) {
    int i = blockIdx.x * blockDim.x + threadIdx.x;
    int stride = gridDim.x * blockDim.x;
    for (; i < n4; i += stride) {
        float4 v = in[i];
        us4 o;
        o.x = f2bf(v.x); o.y = f2bf(v.y); o.z = f2bf(v.z); o.w = f2bf(v.w);
        out[i] = o;
    }
}

// ---------------- pre-pass 2: WT[n][k] = bf16(kernel[k][n]*map[k][n]) ----------------
__global__ __launch_bounds__(256) void maskT(const float* __restrict__ Kn,
                                             const float* __restrict__ Mp,
                                             ushort_t* __restrict__ WT) {
    __shared__ ushort_t t[32][33];
    const int n0 = blockIdx.x * 32;
    const int k0 = blockIdx.y * 32;
    const int tx = threadIdx.x, ty = threadIdx.y;
    #pragma unroll
    for (int i = ty; i < 32; i += 8) {
        size_t idx = (size_t)(k0 + i) * DOUT + (n0 + tx);
        t[i][tx] = f2bf(Kn[idx] * Mp[idx]);
    }
    __syncthreads();
    #pragma unroll
    for (int i = ty; i < 32; i += 8) {
        WT[(size_t)(n0 + i) * DIN + (k0 + tx)] = t[tx][i];
    }
}

// ---------------- main GEMM: m201 window structure ----------------
// 256x256 tile, BK=64, 8 waves (2Mx4N), 512 thr. 8 half-tile LDS slots of
// 16KiB (buf P: A0,A1,B0,B1). Window of tile T (4 phases, buf P=T&1):
//  wph1: rd A(m0-3) 8 + B(n0-1) 4    | stage A0(T+1)->Q | BAR | 16 MFMA | BAR
//  wph2: rd B(n2-3) 4                | stage A1(T+1)->Q | BAR | 16 MFMA | BAR
//  wph3: rd A(m4-7) 8                | stage B0(T+2)->P | BAR | 16 MFMA | BAR
//  wph4: -                           | stage B1(T+2)->P | BAR | 16 MFMA | vmcnt(4) | BAR
// Each half staged in the first phase after its slot's last read (1-phase,
// barrier-hard). vmcnt(4) at window end keeps exactly the 2 newest halves in
// flight and retires tile T+1 fully; never drains except once at T=NT-2.
// Swizzle both sides: byte_col ^= (row&7)<<4; inverse on global src (rule 21).
__global__ __launch_bounds__(512) void gemm8(const ushort_t* __restrict__ A,   // [M][K] bf16
                                             const ushort_t* __restrict__ BT,  // [N][K] bf16
                                             const float* __restrict__ bias,   // [N]
                                             float* __restrict__ C) {          // [M][N] f32
    constexpr int K = DIN, N = DOUT;
    constexpr int NT = K / 64;           // 64 K-tiles
    extern __shared__ char sb[];         // 128 KiB

    const int tid  = threadIdx.x;
    const int lane = tid & 63;
    const int w    = tid >> 6;           // wave 0..7
    const int wr   = w >> 2;             // 0..1  (M half)
    const int wcn  = w & 3;              // 0..3  (N quarter)
    const int l15  = lane & 15;

    // bijective XCD swizzle: 256 blocks, 256 % 8 == 0
    const int orig = blockIdx.y * 8 + blockIdx.x;
    const int swz  = (orig & 7) * 32 + (orig >> 3);
    const int n0   = (swz & 7) * 256;    // N tile
    const int m0   = (swz >> 3) * 256;   // M tile

    // ---- staging: chunk (h,c) = rows c*8..c*8+7 of half h; lane l -> row
    // c*8+(l>>3), LDS 16B slot (l&7); global col16 = (l&7)^(l>>3) (inv swizzle)
    const int srow = lane >> 3;
    const int scol = ((lane & 7) ^ srow) * 8;
    const ushort_t* Ag = A  + (size_t)(m0 + srow) * K + scol;
    const ushort_t* Bg = BT + (size_t)(n0 + srow) * K + scol;

    auto stgA = [&](int buf, int kt, int h, int c) {
        GLOAD16(Ag + (size_t)(h * 128 + c * 8) * K + kt * 64,
                sb + buf * 65536 + h * 16384 + c * 1024);
    };
    auto stgB = [&](int buf, int kt, int h, int c) {
        GLOAD16(Bg + (size_t)(h * 128 + c * 8) * K + kt * 64,
                sb + buf * 65536 + 32768 + h * 16384 + c * 1024);
    };
#define STAGE_A(BUF, KT, H) do { stgA(BUF, KT, H, w); stgA(BUF, KT, H, 8 + w); } while (0)
#define STAGE_B(BUF, KT, H) do { stgB(BUF, KT, H, w); stgB(BUF, KT, H, 8 + w); } while (0)

    // ---- fragment ds_read: row = <mult of 16> + l15 -> row&7 = l15&7 ----
    const int fxor = (l15 & 7) << 4;     // swizzle XOR on byte column
    const int kq   = (lane >> 4) * 16;   // 16B col within K=32 sub-tile

    f32x4 acc[8][4] = {};   // 8 m-frags x 4 n-frags

#define RD_A(BASE, DST, MOFF)                                                  \
    _Pragma("unroll") for (int mm = 0; mm < 4; ++mm)                           \
        _Pragma("unroll") for (int ks = 0; ks < 2; ++ks)                       \
            DST[mm][ks] = *(const bf16x8*)((BASE) + ((MOFF) + mm) * 2048 +     \
                                           l15 * 128 + ((ks * 64 + kq) ^ fxor));
#define RD_B(BASE, DST, NOFF)                                                  \
    _Pragma("unroll") for (int nn = 0; nn < 2; ++nn)                           \
        _Pragma("unroll") for (int ks = 0; ks < 2; ++ks)                       \
            DST[nn][ks] = *(const bf16x8*)((BASE) + ((NOFF) + nn) * 2048 +     \
                                           l15 * 128 + ((ks * 64 + kq) ^ fxor));
#define MFMA16(MH, BF, NB)                                                     \
    __builtin_amdgcn_s_setprio(1);                                             \
    _Pragma("unroll") for (int ks = 0; ks < 2; ++ks)                           \
        _Pragma("unroll") for (int mm = 0; mm < 4; ++mm)                       \
            _Pragma("unroll") for (int nn = 0; nn < 2; ++nn)                   \
                acc[(MH) * 4 + mm][(NB) + nn] =                                \
                    __builtin_amdgcn_mfma_f32_16x16x32_bf16(                   \
                        af[mm][ks], BF[nn][ks],                                \
                        acc[(MH) * 4 + mm][(NB) + nn], 0, 0, 0);               \
    __builtin_amdgcn_s_setprio(0);

#define WINDOW(T, P, SA, SB, WMODE)                                            \
    {                                                                          \
        const char* An_ = sb + (P) * 65536 + wr * 16384;                       \
        const char* Bn_ = sb + (P) * 65536 + 32768 + (wcn >> 1) * 16384 +      \
                          (wcn & 1) * 8192;                                    \
        bf16x8 af[4][2], bfA[2][2], bfB[2][2];                                 \
        /* wph1 */                                                             \
        RD_A(An_, af, 0);                                                      \
        RD_B(Bn_, bfA, 0);                                                     \
        if (SA) { STAGE_A(1 - (P), (T) + 1, 0); }                              \
        BAR(); MFMA16(0, bfA, 0); BAR();                                       \
        /* wph2 */                                                             \
        RD_B(Bn_, bfB, 2);                                                     \
        if (SA) { STAGE_A(1 - (P), (T) + 1, 1); }                              \
        BAR(); MFMA16(0, bfB, 2); BAR();                                       \
        /* wph3 */                                                             \
        RD_A(An_, af, 4);                                                      \
        if (SB) { STAGE_B(P, (T) + 2, 0); }                                    \
        BAR(); MFMA16(1, bfA, 0); BAR();                                       \
        /* wph4 */                                                             \
        if (SB) { STAGE_B(P, (T) + 2, 1); }                                    \
        BAR(); MFMA16(1, bfB, 2);                                              \
        if ((WMODE) == 4) { VMCNT(4); }                                        \
        else if ((WMODE) == 0) { VMCNT(0); }                                   \
        BAR();                                                                 \
    }

    // ---- prologue: tile 0 (buf0) + B halves of tile 1 (buf1); keep B(1) in flight
    STAGE_A(0, 0, 0); STAGE_A(0, 0, 1); STAGE_B(0, 0, 0); STAGE_B(0, 0, 1);
    STAGE_B(1, 1, 0); STAGE_B(1, 1, 1);
    VMCNT(4);   // tile 0's 8 loads retired; B(1)'s 4 in flight
    BAR();

    for (int t = 0; t < NT; t += 2) {
        WINDOW(t, 0, (t + 1 < NT), (t + 2 < NT), (t == NT - 2) ? 0 : 4);
        WINDOW(t + 1, 1, (t + 2 < NT), (t + 3 < NT),
               (t + 1 == NT - 2) ? 0 : ((t + 1 < NT - 2) ? 4 : -1));
    }
#undef WINDOW
#undef MFMA16
#undef RD_A
#undef RD_B
#undef STAGE_A
#undef STAGE_B

    // ---- epilogue: C/D layout col=lane&15, row=(lane>>4)*4+j; fused bias ----
    #pragma unroll
    for (int n = 0; n < 4; ++n) {
        const int col = n0 + wcn * 64 + n * 16 + l15;
        const float bv = bias[col];
        #pragma unroll
        for (int m = 0; m < 8; ++m) {
            const int r0 = m0 + wr * 128 + m * 16 + (lane >> 4) * 4;
            #pragma unroll
            for (int j = 0; j < 4; ++j)
                C[(size_t)(r0 + j) * N + col] = acc[m][n][j] + bv;
        }
    }
}

// ---------------- fallback (ws too small): fp32 LDS-tiled GEMM ----------------
__global__ __launch_bounds__(1024) void gemm_fb(const float* __restrict__ A,
                                                const float* __restrict__ Kn,
                                                const float* __restrict__ Mp,
                                                const float* __restrict__ bias,
                                                float* __restrict__ C) {
    __shared__ float As[32][33];
    __shared__ float Bs[32][33];
    const int tx = threadIdx.x, ty = threadIdx.y;
    const int row = blockIdx.y * 32 + ty;
    const int col = blockIdx.x * 32 + tx;
    float acc = 0.f;
    for (int kt = 0; kt < DIN; kt += 32) {
        As[ty][tx] = A[(size_t)row * DIN + kt + tx];
        size_t bidx = (size_t)(kt + ty) * DOUT + col;
        Bs[ty][tx] = Kn[bidx] * Mp[bidx];
        __syncthreads();
        #pragma unroll
        for (int kk = 0; kk < 32; ++kk)
            acc += As[ty][kk] * Bs[kk][tx];
        __syncthreads();
    }
    C[(size_t)row * DOUT + col] = acc + bias[col];
}

extern "C" void kernel_launch(void* const* d_in, const int* in_sizes, int n_in,
                              void* d_out, int out_size, void* d_ws, size_t ws_size,
                              hipStream_t stream) {
    const float* inputs = (const float*)d_in[0];   // [8192,4096]
    const float* kernel = (const float*)d_in[1];   // [4096,2048]
    const float* bias   = (const float*)d_in[2];   // [2048]
    const float* map    = (const float*)d_in[3];   // [4096,2048]
    float* out = (float*)d_out;                    // [8192,2048]

    const size_t abytes = (size_t)BB * DIN * sizeof(ushort_t);   // 64 MiB
    const size_t wbytes = (size_t)DIN * DOUT * sizeof(ushort_t); // 16 MiB

    if (ws_size >= abytes + wbytes) {
        ushort_t* Abf = (ushort_t*)d_ws;
        ushort_t* WT  = (ushort_t*)((char*)d_ws + abytes);

        static bool attr_set = false;
        if (!attr_set) {
            hipFuncSetAttribute((const void*)gemm8,
                                hipFuncAttributeMaxDynamicSharedMemorySize, 131072);
            attr_set = true;
        }

        convA<<<2048, 256, 0, stream>>>((const float4*)inputs, (us4*)Abf,
                                        (int)((size_t)BB * DIN / 4));
        maskT<<<dim3(DOUT / 32, DIN / 32), dim3(32, 8), 0, stream>>>(kernel, map, WT);
        gemm8<<<dim3(DOUT / 256, BB / 256), 512, 131072, stream>>>(Abf, WT, bias, out);
    } else {
        gemm_fb<<<dim3(DOUT / 32, BB / 32), dim3(32, 32), 0, stream>>>(inputs, kernel, map,
                                                                       bias, out);
    }
}

// Round 12
// 164.180 us; speedup vs baseline: 1.0962x; 1.0086x over previous
//
#include <hip/hip_runtime.h>

#define BB   8192   // batch (M)
#define DIN  4096   // K
#define DOUT 2048   // N

typedef unsigned short ushort_t;
typedef __attribute__((ext_vector_type(8))) short bf16x8;   // 8 bf16 (4 VGPRs)
typedef __attribute__((ext_vector_type(4))) float f32x4;    // 4 fp32 acc

// round-to-nearest-even fp32 -> bf16 bits
__device__ inline ushort_t f2bf(float f) {
    union { float f; unsigned u; } v; v.f = f;
    unsigned u = v.u;
    return (ushort_t)((u + 0x7fffu + ((u >> 16) & 1u)) >> 16);
}

// async global->LDS, 16B per lane; LDS dest = wave-uniform base (+lane*16 implicit)
#define GLOAD16(g, s)                                                        \
    __builtin_amdgcn_global_load_lds(                                        \
        (const __attribute__((address_space(1))) void*)(g),                  \
        (__attribute__((address_space(3))) void*)(s), 16, 0, 0)

#define FENCE()  asm volatile("" ::: "memory")
#define BAR()    do { FENCE(); __builtin_amdgcn_s_barrier(); FENCE(); } while (0)
#define VMCNT(n) asm volatile("s_waitcnt vmcnt(" #n ")" ::: "memory")
#define LGKM(n)  asm volatile("s_waitcnt lgkmcnt(" #n ")" ::: "memory")
#define SCHB()   __builtin_amdgcn_sched_barrier(0)

// ---------------- pre-pass 1: inputs fp32 -> bf16 ----------------
struct __align__(8) us4 { ushort_t x, y, z, w; };

__global__ __launch_bounds__(256) void convA(const float4* __restrict__ in,
                                             us4* __restrict__ out, int n4) {
    int i = blockIdx.x * blockDim.x + threadIdx.x;
    int stride = gridDim.x * blockDim.x;
    for (; i < n4; i += stride) {
        float4 v = in[i];
        us4 o;
        o.x = f2bf(v.x); o.y = f2bf(v.y); o.z = f2bf(v.z); o.w = f2bf(v.w);
        out[i] = o;
    }
}

// ---------------- pre-pass 2: WT[n][k] = bf16(kernel[k][n]*map[k][n]) ----------------
__global__ __launch_bounds__(256) void maskT(const float* __restrict__ Kn,
                                             const float* __restrict__ Mp,
                                             ushort_t* __restrict__ WT) {
    __shared__ ushort_t t[32][33];
    const int n0 = blockIdx.x * 32;
    const int k0 = blockIdx.y * 32;
    const int tx = threadIdx.x, ty = threadIdx.y;
    #pragma unroll
    for (int i = ty; i < 32; i += 8) {
        size_t idx = (size_t)(k0 + i) * DOUT + (n0 + tx);
        t[i][tx] = f2bf(Kn[idx] * Mp[idx]);
    }
    __syncthreads();
    #pragma unroll
    for (int i = ty; i < 32; i += 8) {
        WT[(size_t)(n0 + i) * DIN + (k0 + tx)] = t[tx][i];
    }
}

// ---------------- main GEMM: 256x256, BK=64, 8 waves, single-barrier window ----------
// Diagnosis R3..R11: LDS-read cycles (~2300/tile/CU) ~= MFMA cycles (~2480);
// phase-locked barriers serialize the two pipes -> 45% cap. This window
// overlaps them: ONE barrier + ONE vmcnt(0) per K-tile; inside, 4 MFMA
// clusters of 16 rotate with 4-read groups under counted lgkmcnt +
// sched_barrier (rule 18), so group g+1's LDS drain runs under cluster g's
// MFMAs. Staging (8 gload_lds for t+1, dbuf) issues at window START ->
// vmcnt(0) leash = full window (~2400cy >> 900cy HBM). Single barrier =>
// wave drift < 1 window => stage(Q)/read(P) race-free.
// Swizzle both sides: byte_col ^= (row&7)<<4; inverse on global src (rule 21).
__global__ __launch_bounds__(512) void gemm8(const ushort_t* __restrict__ A,   // [M][K] bf16
                                             const ushort_t* __restrict__ BT,  // [N][K] bf16
                                             const float* __restrict__ bias,   // [N]
                                             float* __restrict__ C) {          // [M][N] f32
    constexpr int K = DIN, N = DOUT;
    constexpr int NT = K / 64;           // 64 K-tiles
    extern __shared__ char sb[];         // 128 KiB

    const int tid  = threadIdx.x;
    const int lane = tid & 63;
    const int w    = tid >> 6;           // wave 0..7
    const int wr   = w >> 2;             // 0..1  (M half)
    const int wcn  = w & 3;              // 0..3  (N quarter)
    const int l15  = lane & 15;

    // bijective XCD swizzle: 256 blocks, 256 % 8 == 0
    const int orig = blockIdx.y * 8 + blockIdx.x;
    const int swz  = (orig & 7) * 32 + (orig >> 3);
    const int n0   = (swz & 7) * 256;    // N tile
    const int m0   = (swz >> 3) * 256;   // M tile

    // ---- staging: chunk (h,c) = rows c*8..c*8+7 of half h; lane l -> row
    // c*8+(l>>3), LDS 16B slot (l&7); global col16 = (l&7)^(l>>3) (inv swizzle)
    const int srow = lane >> 3;
    const int scol = ((lane & 7) ^ srow) * 8;
    const ushort_t* Ag = A  + (size_t)(m0 + srow) * K + scol;
    const ushort_t* Bg = BT + (size_t)(n0 + srow) * K + scol;

    auto stgA = [&](int buf, int kt, int h, int c) {
        GLOAD16(Ag + (size_t)(h * 128 + c * 8) * K + kt * 64,
                sb + buf * 65536 + h * 16384 + c * 1024);
    };
    auto stgB = [&](int buf, int kt, int h, int c) {
        GLOAD16(Bg + (size_t)(h * 128 + c * 8) * K + kt * 64,
                sb + buf * 65536 + 32768 + h * 16384 + c * 1024);
    };
#define STAGE_TILE(BUF, KT)                                                    \
    do {                                                                       \
        stgA(BUF, KT, 0, w); stgA(BUF, KT, 0, 8 + w);                          \
        stgA(BUF, KT, 1, w); stgA(BUF, KT, 1, 8 + w);                          \
        stgB(BUF, KT, 0, w); stgB(BUF, KT, 0, 8 + w);                          \
        stgB(BUF, KT, 1, w); stgB(BUF, KT, 1, 8 + w);                          \
    } while (0)

    // ---- fragment ds_read: row = <mult of 16> + l15 -> row&7 = l15&7 ----
    const int fxor = (l15 & 7) << 4;     // swizzle XOR on byte column
    const int kq   = (lane >> 4) * 16;   // 16B col within K=32 sub-tile

    f32x4 acc[8][4] = {};   // 8 m-frags x 4 n-frags

#define RDA(DST, MH, KS)                                                       \
    _Pragma("unroll") for (int mm = 0; mm < 4; ++mm)                           \
        DST[mm] = *(const bf16x8*)(An_ + ((MH) * 4 + mm) * 2048 + l15 * 128 +  \
                                   (((KS) * 64 + kq) ^ fxor));
#define RDB(DST, KS)                                                           \
    _Pragma("unroll") for (int nn = 0; nn < 4; ++nn)                           \
        DST[nn] = *(const bf16x8*)(Bn_ + nn * 2048 + l15 * 128 +               \
                                   (((KS) * 64 + kq) ^ fxor));
#define MCL(MH, AFS, BFS)                                                      \
    __builtin_amdgcn_s_setprio(1);                                             \
    _Pragma("unroll") for (int mm = 0; mm < 4; ++mm)                           \
        _Pragma("unroll") for (int nn = 0; nn < 4; ++nn)                       \
            acc[(MH) * 4 + mm][nn] = __builtin_amdgcn_mfma_f32_16x16x32_bf16(  \
                AFS[mm], BFS[nn], acc[(MH) * 4 + mm][nn], 0, 0, 0);            \
    __builtin_amdgcn_s_setprio(0);

    // ---- prologue: tile 0 -> buf 0 ----
    STAGE_TILE(0, 0);
    VMCNT(0);
    BAR();

    int cur = 0;
    for (int t = 0; t < NT; ++t) {
        const char* An_ = sb + cur * 65536 + wr * 16384;
        const char* Bn_ = sb + cur * 65536 + 32768 + (wcn >> 1) * 16384 +
                          (wcn & 1) * 8192;
        const bool pf = (t + 1 < NT);
        if (pf) STAGE_TILE(1 - cur, t + 1);   // earliest issue: leash = window

        bf16x8 bf0[4], bf1[4], afA[4], afB[4];
        RDB(bf0, 0); RDA(afA, 0, 0); RDA(afB, 1, 0);   // 12 ds_read in flight
        LGKM(4); SCHB();            // bf0+afA landed (oldest 8)
        MCL(0, afA, bf0);           // 16 MFMA; afB drains underneath
        RDB(bf1, 1); RDA(afA, 0, 1);                   // +8 (afA regs reused)
        LGKM(8); SCHB();            // afB landed
        MCL(1, afB, bf0);           // bf1/afA(ks1) drain underneath
        RDA(afB, 1, 1);                                // +4 (afB regs reused)
        LGKM(4); SCHB();            // bf1+afA(ks1) landed
        MCL(0, afA, bf1);           // afB(ks1) drains underneath
        LGKM(0); SCHB();
        MCL(1, afB, bf1);
        if (pf) { VMCNT(0); }       // staged ~full window ago -> cheap
        BAR();
        cur ^= 1;
    }
#undef MCL
#undef RDA
#undef RDB
#undef STAGE_TILE

    // ---- epilogue: C/D layout col=lane&15, row=(lane>>4)*4+j; fused bias ----
    #pragma unroll
    for (int n = 0; n < 4; ++n) {
        const int col = n0 + wcn * 64 + n * 16 + l15;
        const float bv = bias[col];
        #pragma unroll
        for (int m = 0; m < 8; ++m) {
            const int r0 = m0 + wr * 128 + m * 16 + (lane >> 4) * 4;
            #pragma unroll
            for (int j = 0; j < 4; ++j)
                C[(size_t)(r0 + j) * N + col] = acc[m][n][j] + bv;
        }
    }
}

// ---------------- fallback (ws too small): fp32 LDS-tiled GEMM ----------------
__global__ __launch_bounds__(1024) void gemm_fb(const float* __restrict__ A,
                                                const float* __restrict__ Kn,
                                                const float* __restrict__ Mp,
                                                const float* __restrict__ bias,
                                                float* __restrict__ C) {
    __shared__ float As[32][33];
    __shared__ float Bs[32][33];
    const int tx = threadIdx.x, ty = threadIdx.y;
    const int row = blockIdx.y * 32 + ty;
    const int col = blockIdx.x * 32 + tx;
    float acc = 0.f;
    for (int kt = 0; kt < DIN; kt += 32) {
        As[ty][tx] = A[(size_t)row * DIN + kt + tx];
        size_t bidx = (size_t)(kt + ty) * DOUT + col;
        Bs[ty][tx] = Kn[bidx] * Mp[bidx];
        __syncthreads();
        #pragma unroll
        for (int kk = 0; kk < 32; ++kk)
            acc += As[ty][kk] * Bs[kk][tx];
        __syncthreads();
    }
    C[(size_t)row * DOUT + col] = acc + bias[col];
}

extern "C" void kernel_launch(void* const* d_in, const int* in_sizes, int n_in,
                              void* d_out, int out_size, void* d_ws, size_t ws_size,
                              hipStream_t stream) {
    const float* inputs = (const float*)d_in[0];   // [8192,4096]
    const float* kernel = (const float*)d_in[1];   // [4096,2048]
    const float* bias   = (const float*)d_in[2];   // [2048]
    const float* map    = (const float*)d_in[3];   // [4096,2048]
    float* out = (float*)d_out;                    // [8192,2048]

    const size_t abytes = (size_t)BB * DIN * sizeof(ushort_t);   // 64 MiB
    const size_t wbytes = (size_t)DIN * DOUT * sizeof(ushort_t); // 16 MiB

    if (ws_size >= abytes + wbytes) {
        ushort_t* Abf = (ushort_t*)d_ws;
        ushort_t* WT  = (ushort_t*)((char*)d_ws + abytes);

        static bool attr_set = false;
        if (!attr_set) {
            hipFuncSetAttribute((const void*)gemm8,
                                hipFuncAttributeMaxDynamicSharedMemorySize, 131072);
            attr_set = true;
        }

        convA<<<2048, 256, 0, stream>>>((const float4*)inputs, (us4*)Abf,
                                        (int)((size_t)BB * DIN / 4));
        maskT<<<dim3(DOUT / 32, DIN / 32), dim3(32, 8), 0, stream>>>(kernel, map, WT);
        gemm8<<<dim3(DOUT / 256, BB / 256), 512, 131072, stream>>>(Abf, WT, bias, out);
    } else {
        gemm_fb<<<dim3(DOUT / 32, BB / 32), dim3(32, 32), 0, stream>>>(inputs, kernel, map,
                                                                       bias, out);
    }
}